// Round 1
// 104.355 us; speedup vs baseline: 1.7029x; 1.7029x over previous
//
#include <hip/hip_runtime.h>
#include <hip/hip_bf16.h>
#include <hip/hip_fp8.h>
#include <math.h>

typedef float floatx4 __attribute__((ext_vector_type(4)));
typedef long long i64;
typedef long long i64x2 __attribute__((ext_vector_type(2)));

#define N_ROWS 4096
#define DIM 512
#define LAM 0.5f
#define NT 64   // 128-row block-tiles per dim (8192/128)

#define GLOBAL_AS(p) ((const __attribute__((address_space(1))) void*)(p))
#define LDS_AS(p) ((__attribute__((address_space(3))) void*)(p))

__device__ __forceinline__ unsigned int pack4_fp8(float a, float b, float c, float d) {
    unsigned int u0 = __hip_cvt_float_to_fp8(a, __HIP_SATFINITE, __HIP_E4M3);
    unsigned int u1 = __hip_cvt_float_to_fp8(b, __HIP_SATFINITE, __HIP_E4M3);
    unsigned int u2 = __hip_cvt_float_to_fp8(c, __HIP_SATFINITE, __HIP_E4M3);
    unsigned int u3 = __hip_cvt_float_to_fp8(d, __HIP_SATFINITE, __HIP_E4M3);
    return u0 | (u1 << 8) | (u2 << 16) | (u3 << 24);
}

// One wave per row: L2-normalize 512 fp32 -> fp8 e4m3, stored K-PERMUTED and
// BANK-SWIZZLED. 16-B chunk ch = kt*4+q (kt: 64-k group, q: MFMA quad) holds
// k = kt*64 + {q*8..q*8+7 (lo 8B), 32+q*8..+7 (hi 8B)}; chunk is stored at
// physical position p = ch ^ (row & 7). The XOR only touches the low 3 bits,
// so each 128-B (8-chunk) group is closed under the permutation -> the GEMM
// may stage any BK multiple of 128 as a plain physical byte copy.
__global__ __launch_bounds__(256) void normalize_kernel(
    const float* __restrict__ ei, const float* __restrict__ ej,
    unsigned char* __restrict__ Z, float* __restrict__ out) {
    if (blockIdx.x == 0 && threadIdx.x == 0) out[0] = 0.0f;
    const int w = threadIdx.x >> 6, lane = threadIdx.x & 63;
    const int row = blockIdx.x * 4 + w;                     // [0, 8192)
    const float* __restrict__ src = (row < N_ROWS)
        ? (ei + (size_t)row * DIM)
        : (ej + (size_t)(row - N_ROWS) * DIM);
    const float4* src4 = (const float4*)src;
    float4 v0 = src4[lane];
    float4 v1 = src4[lane + 64];
    float s = v0.x*v0.x + v0.y*v0.y + v0.z*v0.z + v0.w*v0.w
            + v1.x*v1.x + v1.y*v1.y + v1.z*v1.z + v1.w*v1.w;
    #pragma unroll
    for (int off = 32; off; off >>= 1) s += __shfl_xor(s, off);
    const float r = rsqrtf(s);

    __shared__ __align__(16) unsigned char buf[4][512];     // k-linear fp8 rows
    ((unsigned int*)buf[w])[lane]      = pack4_fp8(v0.x*r, v0.y*r, v0.z*r, v0.w*r);
    ((unsigned int*)buf[w])[lane + 64] = pack4_fp8(v1.x*r, v1.y*r, v1.z*r, v1.w*r);
    __syncthreads();

    // full-wave permuted store: lane = kt*8 + q*2 + h, 8 B each
    const int kt = lane >> 3, q = (lane >> 1) & 3, h = lane & 1;
    i64 val = *(const i64*)(buf[w] + kt * 64 + h * 32 + q * 8);
    const int p = (kt * 4 + q) ^ (row & 7);                 // bank swizzle
    *(i64*)(Z + (size_t)row * DIM + p * 16 + h * 8) = val;
}

// Fused S = Z.Z^T (fp8 16x16x32 MFMA) + loss reduction.
// 128x128 block, 4 waves (2x2 of 64x64). NEW this round (rocprof showed
// MfmaUtil 11% / VALUBusy 10% / HBM 2% -> pure serialization stall):
//   * K split into 4 stages of BK=128, DOUBLE-BUFFERED (2x16KB A + 2x16KB B
//     = 64 KB LDS, still 2 blocks/CU). Stage t+2 is prefetched while stage t
//     computes.
//   * Raw s_barrier + COUNTED `s_waitcnt vmcnt(8)` (never 0 in the main loop)
//     replaces __syncthreads(), so prefetch loads stay in flight across the
//     barrier (T3+T4). __syncthreads' implicit vmcnt(0) drain was the stall.
//   * s_setprio(1) around each MFMA cluster (T5).
//   * Atomic traffic cut 4x: wave partials -> LDS -> ONE atomicAdd per block
//     (8320 same-address atomics were a candidate pacer).
// Staging is lane-monotone (global_load_lds writes base + lane*16): wave w,
// instr l copies rows l*32+w*8..+7 (8 rows x 128 B contiguous in LDS).
// Fragments: one ds_read_b128 per frag per K=64; stage-local chunk
// pp = (g*4+q) ^ (row&7) by the store-side swizzle.
// Triangular grid; off-diag wave-tiles x2; positives on tn==tm+64 diagonals.
__global__ __launch_bounds__(256, 2) void simloss_kernel(
    const unsigned char* __restrict__ Z, float* __restrict__ out) {
    // --- triangular decode ---
    const int id = blockIdx.x;
    int bm = (int)((2*NT + 1 - sqrtf((float)((2*NT+1)*(2*NT+1)) - 8.0f * (float)id)) * 0.5f);
    if (bm < 0) bm = 0; if (bm > NT-1) bm = NT-1;
    while ((bm + 1) * NT - ((bm + 1) * bm) / 2 <= id) ++bm;
    while (bm * NT - (bm * (bm - 1)) / 2 > id) --bm;
    const int bn = bm + (id - (bm * NT - (bm * (bm - 1)) / 2));

    const int tid = threadIdx.x;
    const int w = tid >> 6, lane = tid & 63;
    const int q = lane >> 4, m16 = lane & 15;
    const int wm = w & 1, wn = w >> 1;
    const int tm = bm * 2 + wm, tn = bn * 2 + wn;   // 64-row tile ids [0,128)

    __shared__ __align__(16) unsigned char As[2][128 * 128];  // 16 KB per buf
    __shared__ __align__(16) unsigned char Bs[2][128 * 128];
    __shared__ float red[4];

    // staging: instr l of wave w: rows l*32 + w*8 + (lane>>3), byte (lane&7)*16
    // LDS slot = l*4096 + w*1024 + lane*16  (lane-linear physical byte copy)
    const unsigned char* stA = Z + (size_t)(bm * 128 + w * 8 + (lane >> 3)) * DIM + (lane & 7) * 16;
    const unsigned char* stB = Z + (size_t)(bn * 128 + w * 8 + (lane >> 3)) * DIM + (lane & 7) * 16;
    const int ldsOff = w * 1024;

    // fragment bases: LDS row r (128 B) at r*128; chunk col swizzled by (m16&7)
    const int fragSwz = m16 & 7;

    floatx4 acc[4][4] = {};

    // --- prologue: prefetch stages 0 and 1 (8 loads each) ---
    #pragma unroll
    for (int l = 0; l < 4; ++l) {
        __builtin_amdgcn_global_load_lds(GLOBAL_AS(stA + (size_t)l * 32 * DIM),
                                         LDS_AS(&As[0][ldsOff + l * 4096]), 16, 0, 0);
        __builtin_amdgcn_global_load_lds(GLOBAL_AS(stB + (size_t)l * 32 * DIM),
                                         LDS_AS(&Bs[0][ldsOff + l * 4096]), 16, 0, 0);
    }
    #pragma unroll
    for (int l = 0; l < 4; ++l) {
        __builtin_amdgcn_global_load_lds(GLOBAL_AS(stA + (size_t)l * 32 * DIM + 128),
                                         LDS_AS(&As[1][ldsOff + l * 4096]), 16, 0, 0);
        __builtin_amdgcn_global_load_lds(GLOBAL_AS(stB + (size_t)l * 32 * DIM + 128),
                                         LDS_AS(&Bs[1][ldsOff + l * 4096]), 16, 0, 0);
    }

    // --- main loop: 4 stages of BK=128, 2-deep pipeline ---
    #pragma unroll
    for (int s = 0; s < 4; ++s) {
        // wait for MY stage-s loads; leave the (up to 8) newer loads in flight
        if (s < 3) { asm volatile("s_waitcnt vmcnt(8)" ::: "memory"); }
        else       { asm volatile("s_waitcnt vmcnt(0)" ::: "memory"); }
        __builtin_amdgcn_sched_barrier(0);
        __builtin_amdgcn_s_barrier();          // now ALL waves' stage-s data is in LDS

        const unsigned char* fraA = &As[s & 1][(wm * 64 + m16) * 128];
        const unsigned char* fraB = &Bs[s & 1][(wn * 64 + m16) * 128];
        #pragma unroll
        for (int g = 0; g < 2; ++g) {          // two K=64 groups per stage
            const int cOff = ((g * 4 + q) ^ fragSwz) << 4;   // swizzled 16-B chunk
            i64x2 af[4], bf[4];
            #pragma unroll
            for (int i = 0; i < 4; ++i) af[i] = *(const i64x2*)(fraA + i * 16 * 128 + cOff);
            #pragma unroll
            for (int j = 0; j < 4; ++j) bf[j] = *(const i64x2*)(fraB + j * 16 * 128 + cOff);
            __builtin_amdgcn_s_setprio(1);
            #pragma unroll
            for (int i = 0; i < 4; ++i)
                #pragma unroll
                for (int j = 0; j < 4; ++j) {
                    acc[i][j] = __builtin_amdgcn_mfma_f32_16x16x32_fp8_fp8(af[i].x, bf[j].x, acc[i][j], 0, 0, 0);
                    acc[i][j] = __builtin_amdgcn_mfma_f32_16x16x32_fp8_fp8(af[i].y, bf[j].y, acc[i][j], 0, 0, 0);
                }
            __builtin_amdgcn_s_setprio(0);
        }

        if (s < 2) {
            // all waves done READING buf[s&1] -> safe to overwrite with stage s+2
            asm volatile("" ::: "memory");
            __builtin_amdgcn_s_barrier();
            #pragma unroll
            for (int l = 0; l < 4; ++l) {
                __builtin_amdgcn_global_load_lds(GLOBAL_AS(stA + (size_t)l * 32 * DIM + (s + 2) * 128),
                                                 LDS_AS(&As[s & 1][ldsOff + l * 4096]), 16, 0, 0);
                __builtin_amdgcn_global_load_lds(GLOBAL_AS(stB + (size_t)l * 32 * DIM + (s + 2) * 128),
                                                 LDS_AS(&Bs[s & 1][ldsOff + l * 4096]), 16, 0, 0);
            }
        }
        // s>=2: stage 3 was already prefetched; buf[0] is never reused -> no
        // trailing barrier needed (leading barrier of s=3 still syncs all waves).
    }

    // --- epilogue: C/D map row = i*16 + q*4 + r, col = j*16 + m16 (tile-local) ---
    const int rowBase = tm * 64 + q * 4;
    const int colBase = tn * 64 + m16;
    float negsum = 0.0f, possum = 0.0f;
    #pragma unroll
    for (int j = 0; j < 4; ++j) {
        const int cg = colBase + j * 16;
        float p = 1.0f;
        #pragma unroll
        for (int i = 0; i < 4; ++i) {
            const int rg0 = rowBase + i * 16;
            #pragma unroll
            for (int r = 0; r < 4; ++r) {
                const float sv = acc[i][j][r];
                float e = __expf(sv - LAM);
                if (rg0 + r == cg) e = 0.0f;          // mask main diagonal
                p *= (1.0f + e);
                if (cg == rg0 + r + N_ROWS)           // positive pair (k, k+N)
                    possum += log1pf(expf(-sv + LAM));
            }
        }
        negsum += __logf(p);
    }
    // diag-block lower-triangle waves are redundant: weight 0; off-diag x2.
    const float wgt = (tn < tm) ? 0.0f : ((tm == tn) ? 1.0f : 2.0f);
    negsum *= wgt;

    #pragma unroll
    for (int off = 32; off; off >>= 1) {
        negsum += __shfl_xor(negsum, off);
        possum += __shfl_xor(possum, off);
    }
    // block-level reduction: ONE atomic per block (was 4) to cut same-address
    // atomic serialization 8320 -> 2080.
    const float part = negsum * (1.0f / (12.0f * (float)N_ROWS))
                     + possum * (1.0f / (float)N_ROWS);
    if (lane == 0) red[w] = part;
    __syncthreads();
    if (tid == 0) atomicAdd(out, red[0] + red[1] + red[2] + red[3]);
}

extern "C" void kernel_launch(void* const* d_in, const int* in_sizes, int n_in,
                              void* d_out, int out_size, void* d_ws, size_t ws_size,
                              hipStream_t stream) {
    const float* ei = (const float*)d_in[0];
    const float* ej = (const float*)d_in[1];
    float* out = (float*)d_out;
    unsigned char* Z = (unsigned char*)d_ws;  // 8192*512 fp8 = 4 MB scratch

    normalize_kernel<<<2048, 256, 0, stream>>>(ei, ej, Z, out);
    simloss_kernel<<<NT * (NT + 1) / 2, 256, 0, stream>>>(Z, out);
}

// Round 2
// 100.759 us; speedup vs baseline: 1.7637x; 1.0357x over previous
//
#include <hip/hip_runtime.h>
#include <hip/hip_bf16.h>
#include <hip/hip_fp8.h>
#include <math.h>

typedef float floatx4 __attribute__((ext_vector_type(4)));
typedef long long i64;
typedef long long i64x2 __attribute__((ext_vector_type(2)));

#define N_ROWS 4096
#define DIM 512
#define LAM 0.5f
#define NT 64                      // 128-row block-tiles per dim (8192/128)
#define NTILES (NT * (NT + 1) / 2) // 2080 triangular tiles
#define GRID 512                   // persistent blocks: 2/CU exactly

#define GLOBAL_AS(p) ((const __attribute__((address_space(1))) void*)(p))
#define LDS_AS(p) ((__attribute__((address_space(3))) void*)(p))

__device__ __forceinline__ unsigned int pack4_fp8(float a, float b, float c, float d) {
    unsigned int u0 = __hip_cvt_float_to_fp8(a, __HIP_SATFINITE, __HIP_E4M3);
    unsigned int u1 = __hip_cvt_float_to_fp8(b, __HIP_SATFINITE, __HIP_E4M3);
    unsigned int u2 = __hip_cvt_float_to_fp8(c, __HIP_SATFINITE, __HIP_E4M3);
    unsigned int u3 = __hip_cvt_float_to_fp8(d, __HIP_SATFINITE, __HIP_E4M3);
    return u0 | (u1 << 8) | (u2 << 16) | (u3 << 24);
}

// One wave per row: L2-normalize 512 fp32 -> fp8 e4m3, stored K-PERMUTED and
// BANK-SWIZZLED. 16-B chunk ch = kt*4+q (kt: 64-k group, q: MFMA quad) holds
// k = kt*64 + {q*8..q*8+7 (lo 8B), 32+q*8..+7 (hi 8B)}; chunk is stored at
// physical position p = ch ^ (row & 7). The XOR only touches the low 3 bits,
// so each 128-B (8-chunk) group is closed under the permutation -> the GEMM
// may stage any BK multiple of 128 as a plain physical byte copy.
__global__ __launch_bounds__(256) void normalize_kernel(
    const float* __restrict__ ei, const float* __restrict__ ej,
    unsigned char* __restrict__ Z, float* __restrict__ out) {
    if (blockIdx.x == 0 && threadIdx.x == 0) out[0] = 0.0f;
    const int w = threadIdx.x >> 6, lane = threadIdx.x & 63;
    const int row = blockIdx.x * 4 + w;                     // [0, 8192)
    const float* __restrict__ src = (row < N_ROWS)
        ? (ei + (size_t)row * DIM)
        : (ej + (size_t)(row - N_ROWS) * DIM);
    const float4* src4 = (const float4*)src;
    float4 v0 = src4[lane];
    float4 v1 = src4[lane + 64];
    float s = v0.x*v0.x + v0.y*v0.y + v0.z*v0.z + v0.w*v0.w
            + v1.x*v1.x + v1.y*v1.y + v1.z*v1.z + v1.w*v1.w;
    #pragma unroll
    for (int off = 32; off; off >>= 1) s += __shfl_xor(s, off);
    const float r = rsqrtf(s);

    __shared__ __align__(16) unsigned char buf[4][512];     // k-linear fp8 rows
    ((unsigned int*)buf[w])[lane]      = pack4_fp8(v0.x*r, v0.y*r, v0.z*r, v0.w*r);
    ((unsigned int*)buf[w])[lane + 64] = pack4_fp8(v1.x*r, v1.y*r, v1.z*r, v1.w*r);
    __syncthreads();

    // full-wave permuted store: lane = kt*8 + q*2 + h, 8 B each
    const int kt = lane >> 3, q = (lane >> 1) & 3, h = lane & 1;
    i64 val = *(const i64*)(buf[w] + kt * 64 + h * 32 + q * 8);
    const int p = (kt * 4 + q) ^ (row & 7);                 // bank swizzle
    *(i64*)(Z + (size_t)row * DIM + p * 16 + h * 8) = val;
}

// Fused S = Z.Z^T (fp8 16x16x32 MFMA) + loss reduction.
// 128x128 tile, 4 waves (2x2 of 64x64), BK=128 double-buffered (64 KB LDS,
// 2 blocks/CU). NEW this round (round-1 analysis: simloss ~44 us vs 17 us
// MFMA floor; co-resident blocks phase-locked on 6 barriers/tile + cold
// prologue + exposed epilogue per tile):
//   * PERSISTENT blocks: grid=512, each block streams 4-5 tiles. The stage
//     pipeline is CONTINUOUS across tiles - loads for global stage g+1 are
//     issued right after the single barrier at the top of stage g (the
//     barrier proves buf[(g+1)&1]'s readers from stage g-1 are done).
//   * ONE barrier per stage (was 2); no vmcnt(0) tile drains; only one cold
//     prologue per block; next tile's stage-0 loads fly under the epilogue.
//   * Epilogue accumulates in registers; ONE atomic per block at the end.
//   * Wave-uniform guards: positives path only when tn==tm+64; epilogue
//     skipped entirely for wgt==0 (diagonal lower-triangle) waves.
__global__ __launch_bounds__(256, 2) void simloss_kernel(
    const unsigned char* __restrict__ Z, float* __restrict__ out) {
    const int tid = threadIdx.x;
    const int w = tid >> 6, lane = tid & 63;
    const int q = lane >> 4, m16 = lane & 15;
    const int wm = w & 1, wn = w >> 1;

    __shared__ __align__(16) unsigned char As[2][128 * 128];  // 16 KB per buf
    __shared__ __align__(16) unsigned char Bs[2][128 * 128];
    __shared__ float red[4];

    const int ldsOff = w * 1024;
    const int fragSwz = m16 & 7;
    // staging row/col offsets within a 128-row panel (lane-monotone copy)
    const int stRow = w * 8 + (lane >> 3);
    const int stCol = (lane & 7) * 16;

    const int bid = blockIdx.x;
    const int nMine = 4 + (bid < (NTILES - 4 * GRID));   // 2080-2048=32 extras

    // --- tile decode (float-seeded triangular index) ---
    auto decode = [](int id, int& bm, int& bn) {
        int m = (int)((2*NT + 1 - sqrtf((float)((2*NT+1)*(2*NT+1)) - 8.0f * (float)id)) * 0.5f);
        if (m < 0) m = 0; if (m > NT-1) m = NT-1;
        while ((m + 1) * NT - ((m + 1) * m) / 2 <= id) ++m;
        while (m * NT - (m * (m - 1)) / 2 > id) --m;
        bm = m;
        bn = m + (id - (m * NT - (m * (m - 1)) / 2));
    };

    int id = bid;
    int bm, bn; decode(id, bm, bn);
    const unsigned char* stA = Z + (size_t)(bm * 128 + stRow) * DIM + stCol;
    const unsigned char* stB = Z + (size_t)(bn * 128 + stRow) * DIM + stCol;

    float negsum = 0.0f, possum = 0.0f;

    // issue one BK=128 stage (8 x global_load_lds width-16) into buffer par
    #define ISSUE(par, pA, pB, kOff)                                             \
        _Pragma("unroll")                                                        \
        for (int l = 0; l < 4; ++l) {                                            \
            __builtin_amdgcn_global_load_lds(GLOBAL_AS((pA) + (size_t)l * 32 * DIM + (kOff)), \
                                             LDS_AS(&As[par][ldsOff + l * 4096]), 16, 0, 0);  \
            __builtin_amdgcn_global_load_lds(GLOBAL_AS((pB) + (size_t)l * 32 * DIM + (kOff)), \
                                             LDS_AS(&Bs[par][ldsOff + l * 4096]), 16, 0, 0);  \
        }

    // prologue: tile 0, stage 0 -> buf 0
    ISSUE(0, stA, stB, 0)

    for (int mt = 0; mt < nMine; ++mt) {
        const int tm = bm * 2 + wm, tn = bn * 2 + wn;
        // decode the NEXT tile early (VALU, hides under compute)
        const bool hasNext = (mt + 1 < nMine);
        int nbm = 0, nbn = 0;
        const unsigned char *nA = stA, *nB = stB;
        if (hasNext) {
            decode(id + GRID, nbm, nbn);
            nA = Z + (size_t)(nbm * 128 + stRow) * DIM + stCol;
            nB = Z + (size_t)(nbn * 128 + stRow) * DIM + stCol;
        }

        floatx4 acc[4][4] = {};

        #pragma unroll
        for (int s = 0; s < 4; ++s) {
            const int par = (mt * 4 + s) & 1;          // buffer parity (continuous)
            // wait for THIS stage's 8 loads (nothing newer is in flight:
            // next stage is issued after the barrier below)
            asm volatile("s_waitcnt vmcnt(0)" ::: "memory");
            __builtin_amdgcn_sched_barrier(0);
            __builtin_amdgcn_s_barrier();              // readers of buf[par^1] done
            // issue stage g+1 into buf[par^1]
            if (s < 3)        { ISSUE(par ^ 1, stA, stB, (s + 1) * 128) }
            else if (hasNext) { ISSUE(par ^ 1, nA, nB, 0) }

            const unsigned char* fraA = &As[par][(wm * 64 + m16) * 128];
            const unsigned char* fraB = &Bs[par][(wn * 64 + m16) * 128];
            #pragma unroll
            for (int g = 0; g < 2; ++g) {              // two K=64 groups
                const int cOff = ((g * 4 + q) ^ fragSwz) << 4;
                i64x2 af[4], bf[4];
                #pragma unroll
                for (int i = 0; i < 4; ++i) af[i] = *(const i64x2*)(fraA + i * 16 * 128 + cOff);
                #pragma unroll
                for (int j = 0; j < 4; ++j) bf[j] = *(const i64x2*)(fraB + j * 16 * 128 + cOff);
                __builtin_amdgcn_s_setprio(1);
                #pragma unroll
                for (int i = 0; i < 4; ++i)
                    #pragma unroll
                    for (int j = 0; j < 4; ++j) {
                        acc[i][j] = __builtin_amdgcn_mfma_f32_16x16x32_fp8_fp8(af[i].x, bf[j].x, acc[i][j], 0, 0, 0);
                        acc[i][j] = __builtin_amdgcn_mfma_f32_16x16x32_fp8_fp8(af[i].y, bf[j].y, acc[i][j], 0, 0, 0);
                    }
                __builtin_amdgcn_s_setprio(0);
            }
        }

        // --- per-tile epilogue (no barriers; next tile's loads in flight) ---
        // C/D map: row = i*16 + q*4 + r, col = j*16 + m16 (tile-local)
        const float wgt = (tn < tm) ? 0.0f : ((tm == tn) ? 1.0f : 2.0f);
        const bool hasPos = (tn == tm + 64);           // wave-uniform
        if (wgt != 0.0f) {
            const int rowBase = tm * 64 + q * 4;
            const int colBase = tn * 64 + m16;
            float nacc = 0.0f;
            #pragma unroll
            for (int j = 0; j < 4; ++j) {
                const int cg = colBase + j * 16;
                float p = 1.0f;
                #pragma unroll
                for (int i = 0; i < 4; ++i) {
                    const int rg0 = rowBase + i * 16;
                    #pragma unroll
                    for (int r = 0; r < 4; ++r) {
                        const float sv = acc[i][j][r];
                        float e = __expf(sv - LAM);
                        if (rg0 + r == cg) e = 0.0f;   // mask main diagonal
                        p *= (1.0f + e);
                        if (hasPos && cg == rg0 + r + N_ROWS)  // positive pair
                            possum += log1pf(expf(-sv + LAM));
                    }
                }
                nacc += __logf(p);
            }
            negsum += nacc * wgt;
        }

        id += GRID; bm = nbm; bn = nbn; stA = nA; stB = nB;
    }

    // --- block reduction: one atomic per block ---
    #pragma unroll
    for (int off = 32; off; off >>= 1) {
        negsum += __shfl_xor(negsum, off);
        possum += __shfl_xor(possum, off);
    }
    const float part = negsum * (1.0f / (12.0f * (float)N_ROWS))
                     + possum * (1.0f / (float)N_ROWS);
    if (lane == 0) red[w] = part;
    __syncthreads();
    if (tid == 0) atomicAdd(out, red[0] + red[1] + red[2] + red[3]);
    #undef ISSUE
}

extern "C" void kernel_launch(void* const* d_in, const int* in_sizes, int n_in,
                              void* d_out, int out_size, void* d_ws, size_t ws_size,
                              hipStream_t stream) {
    const float* ei = (const float*)d_in[0];
    const float* ej = (const float*)d_in[1];
    float* out = (float*)d_out;
    unsigned char* Z = (unsigned char*)d_ws;  // 8192*512 fp8 = 4 MB scratch

    normalize_kernel<<<2048, 256, 0, stream>>>(ei, ej, Z, out);
    simloss_kernel<<<GRID, 256, 0, stream>>>(Z, out);
}